// Round 9
// baseline (445.636 us; speedup 1.0000x reference)
//
#include <hip/hip_runtime.h>
#include <stdint.h>

// B=16, S=2048, D=128 attention, per-query scale folded into Q (with log2e),
// online softmax in exp2 domain, exact JAX partitionable-threefry dropout
// (key 42, p=0.1), @V.
// History: R10 259.6us; R13 264 (f16 workspace, reg-direct K, Occ 39%);
// R14 275 (barrier-free); R15 271; R16 284.7 (XCD swizzle: FETCH 123->19MB
// -- keep; sched_barrier: spills +6MB WRITE, +13us -- revert).
// Round 17 (this): SWAPPED QK^T -> in-register P, no LDS roundtrip.
//  - QK^T = mfma(A=K_frag, B=Q_frag) gives S[key=quad*4+r][q=l15]; that IS
//    the PV A-frag layout for 16x16x16 MFMAs split by 16-key halves:
//    ap[n] = pack(pm[n][0..3]) in-lane.  Deletes 8 ds_write + fence +
//    ds_read + 32 DPP ops per iter; softmax row-max = 7 in-lane fmax +
//    2 shfl_xor.  Dropout jq/jcol transposed to match (q=l15).
//  - PV: 16x mfma_f32_16x16x16f16 (2 n-halves x 8 d8), V frags 16x8B.
//  - epilogue: both kph waves publish m/l via LDS (kph0's regs are per-q=l15,
//    not per-output-row), then merge as before.

#define B_ 16
#define S_ 2048
#define D_ 128
#define TQ 64     // q rows per block (4 subtiles x 16)
#define TK 64     // keys per iteration (each kph-wave consumes 32)
#define NT (S_ / TK)
#define VTILE (64 * D_)                   // dense V^T tile: 8192 f16 = 16 KB
#define KST_ELEMS ((size_t)B_ * S_ * D_)  // 4194304 f16 = 8 MB

typedef float f32x4 __attribute__((ext_vector_type(4)));
typedef _Float16 f16x8 __attribute__((ext_vector_type(8)));
typedef _Float16 f16x4 __attribute__((ext_vector_type(4)));

// threefry2x32, 20 rounds, key = (0, 42)  [jax.random.key(42)]
__device__ __forceinline__ uint2 threefry2x32_0_42(uint32_t x0, uint32_t x1) {
  const uint32_t k0 = 0u, k1 = 42u;
  const uint32_t k2 = 0x1BD11BDAu ^ k0 ^ k1;
  x0 += k0; x1 += k1;
#define TFR(r) { x0 += x1; x1 = __builtin_rotateleft32(x1, r); x1 ^= x0; }
  TFR(13) TFR(15) TFR(26) TFR(6)
  x0 += k1; x1 += k2 + 1u;
  TFR(17) TFR(29) TFR(16) TFR(24)
  x0 += k2; x1 += k0 + 2u;
  TFR(13) TFR(15) TFR(26) TFR(6)
  x0 += k0; x1 += k1 + 3u;
  TFR(17) TFR(29) TFR(16) TFR(24)
  x0 += k1; x1 += k2 + 4u;
  TFR(13) TFR(15) TFR(26) TFR(6)
  x0 += k2; x1 += k0 + 5u;
#undef TFR
  return make_uint2(x0, x1);
}

// HW-verified: partitionable path, counter (0, j), xor-fold.
__device__ __forceinline__ uint32_t jax_bits(uint32_t j) {
  const uint2 tf = threefry2x32_0_42(0u, j);
  return tf.x ^ tf.y;
}

// ---- fused pre-pass: K f32->f16 copy  +  V f32->f16 transpose (dense) ----
// grid: 4096 K-blocks + 512 V-blocks (b = idx>>5, kt = idx&31)
__global__ __launch_bounds__(256)
void prep_kv(const float* __restrict__ K, const float* __restrict__ V,
             _Float16* __restrict__ Kst, _Float16* __restrict__ Vst) {
  __shared__ _Float16 sT[64 * 132];   // [key][d] padded (V branch only)
  const int t = threadIdx.x;
  if (blockIdx.x < 4096) {
    const size_t i = ((size_t)blockIdx.x * 256 + t) * 4;
    const float4 x = *(const float4*)(K + i);
    f16x4 h = {(_Float16)x.x, (_Float16)x.y, (_Float16)x.z, (_Float16)x.w};
    *(f16x4*)(Kst + i) = h;
    return;
  }
  const int idx = blockIdx.x - 4096;
  const int b = idx >> 5, kt = idx & 31;
  const int key = t >> 2, dq = t & 3;
  const float* vp = V + ((size_t)(b * S_ + kt * 64 + key)) * D_ + dq * 32;
  #pragma unroll
  for (int i = 0; i < 8; ++i) {
    const float4 x = *(const float4*)(vp + i * 4);
    _Float16* d = &sT[key * 132 + dq * 32 + i * 4];
    d[0] = (_Float16)x.x; d[1] = (_Float16)x.y;
    d[2] = (_Float16)x.z; d[3] = (_Float16)x.w;
  }
  __syncthreads();
  _Float16* tile = Vst + (size_t)(b * NT + kt) * VTILE;
  #pragma unroll
  for (int it = 0; it < 4; ++it) {
    const int i2 = t * 4 + it;           // 1024 items: (d:128, kg:8)
    const int d = i2 >> 3, kg = i2 & 7;
    f16x8 v;
    #pragma unroll
    for (int j = 0; j < 8; ++j) v[j] = sT[(kg * 8 + j) * 132 + d];
    *(f16x8*)&tile[d * 64 + kg * 8] = v;
  }
}

__global__ __launch_bounds__(512)
__attribute__((amdgpu_waves_per_eu(4, 4)))
void attn_mfma_kernel(const float* __restrict__ Q, const _Float16* __restrict__ Kst,
                      const _Float16* __restrict__ Vst, const float* __restrict__ ISF,
                      const float* __restrict__ DP, float* __restrict__ OUT) {
  __shared__ __align__(16) char smem[33792];
  // epilogue-only LDS:
  float* const sO1 = (float*)smem;                      // 64x128 f32 = 32768 B
  float* const sM  = (float*)(smem + 32768);            // [kph][64] = 512 B
  float* const sL  = (float*)(smem + 33280);            // [kph][64] = 512 B

  const int t    = threadIdx.x;
  const int lane = t & 63;
  const int l15  = lane & 15;
  const int quad = lane >> 4;
  const int w    = t >> 6;       // 0..7
  const int qsub = w >> 1;       // q-subtile (16 rows), 0..3
  const int kph  = w & 1;        // key phase: 0 = keys [0,32), 1 = [32,64)

  // ---- XCD-aware decode of the 1D block index ----
  const int l    = blockIdx.x;           // 0..511
  const int b    = (l & 7) + 8 * (l >> 8);
  const int qt   = (l >> 3) & 31;
  const int qb   = qt * TQ + qsub * 16;

  const float kp = 1.0f - DP[0];
  const uint32_t TH9 = (__float_as_uint(1.0f + kp) & 0x7FFFFFu) << 9;

  // per-lane softmax state for q = qb + l15 (replicated across quads)
  float m_ = -INFINITY, l_ = 0.0f;
  const uint32_t jq = ((uint32_t)b << 22)
                    + (uint32_t)(qb + l15) * (uint32_t)S_;

  // ---- Q fragment, f16, 1/isf and log2(e) folded in.
  //      Serves as the MFMA *B*-operand of swapped QK^T:
  //      B[k=d (quad*8+j within 32-slice)][col=q=l15]. ----
  f16x8 qf[4];
  {
    const int qrow = qb + l15;
    const float qs = 1.4426950408889634f / ISF[b * S_ + qrow];
    const float* qp = Q + ((size_t)(b * S_ + qrow)) * D_;
    #pragma unroll
    for (int c = 0; c < 4; ++c) {
      const float4 a  = *(const float4*)(qp + c * 32 + quad * 8);
      const float4 d2 = *(const float4*)(qp + c * 32 + quad * 8 + 4);
      const float xs[8] = {a.x, a.y, a.z, a.w, d2.x, d2.y, d2.z, d2.w};
      f16x8 h;
      #pragma unroll
      for (int j = 0; j < 8; ++j) h[j] = (_Float16)(xs[j] * qs);
      qf[c] = h;
    }
  }

  f32x4 accO[8];   // O[q=quad*4+r][d=d8*16+l15]
  #pragma unroll
  for (int i = 0; i < 8; ++i) accO[i] = (f32x4){0.f, 0.f, 0.f, 0.f};

  // incremental K/V pointers
  const _Float16* kb = Kst + ((size_t)(b * S_ + kph * 32)) * D_;
  const _Float16* vb = Vst + (size_t)b * NT * VTILE + kph * 32;

  // ================= BARRIER-FREE MAIN LOOP =================
  for (int kt = 0; kt < NT; ++kt, kb += TK * D_, vb += VTILE) {
    // ---- K fragments (MFMA A-operand): A[row=key16][k=d] ----
    f16x8 kf[2][4];
    #pragma unroll
    for (int n = 0; n < 2; ++n)
      #pragma unroll
      for (int c = 0; c < 4; ++c)
        kf[n][c] = *(const f16x8*)(kb + (n * 16 + l15) * D_ + c * 32 + quad * 8);

    // ---- V fragments for 16x16x16 PV: B[k=key_local=quad*4+j][col=d] ----
    f16x4 vf[2][8];
    #pragma unroll
    for (int n = 0; n < 2; ++n)
      #pragma unroll
      for (int d8 = 0; d8 < 8; ++d8)
        vf[n][d8] = *(const f16x4*)&vb[(d8 * 16 + l15) * 64 + n * 16 + quad * 4];

    // ---- threefry dropout bits for (q=l15, key=kt*64+kph*32+n*16+quad*4+r) ----
    uint32_t rb[2][4];
    #pragma unroll
    for (int n = 0; n < 2; ++n) {
      const uint32_t jc0 = (uint32_t)(kt * TK + kph * 32 + n * 16 + quad * 4);
      #pragma unroll
      for (int r = 0; r < 4; ++r)
        rb[n][r] = jax_bits(jq + jc0 + r);
    }

    // ---- swapped QK^T: S[key][q], s[n][r] = S[n*16+quad*4+r][l15] ----
    f32x4 s[2];
    #pragma unroll
    for (int n = 0; n < 2; ++n) {
      f32x4 a0 = (f32x4){0.f, 0.f, 0.f, 0.f};
      #pragma unroll
      for (int c = 0; c < 4; ++c)
        a0 = __builtin_amdgcn_mfma_f32_16x16x32_f16(kf[n][c], qf[c], a0, 0, 0, 0);
      s[n] = a0;
    }

    // ---- online softmax (exp2 domain), per-lane row state (q=l15) ----
    float pmax = fmaxf(fmaxf(fmaxf(s[0][0], s[0][1]), fmaxf(s[0][2], s[0][3])),
                       fmaxf(fmaxf(s[1][0], s[1][1]), fmaxf(s[1][2], s[1][3])));
    pmax = fmaxf(pmax, __shfl_xor(pmax, 16));
    pmax = fmaxf(pmax, __shfl_xor(pmax, 32));
    if (__ballot(pmax > m_ + 8.0f) != 0ull) {   // T13 deferred rescale
      const float mnew = fmaxf(m_, pmax);
      const float alpha = __builtin_amdgcn_exp2f(m_ - mnew);
      m_ = mnew;
      l_ *= alpha;
      // accO rows are q = quad*4 + r; fetch each row's alpha from the lane
      // (same quad) whose l15 == that row.  (replicated across quads)
      #pragma unroll
      for (int r = 0; r < 4; ++r) {
        const float ar = __shfl(alpha, (lane & 48) + quad * 4 + r);
        #pragma unroll
        for (int d8 = 0; d8 < 8; ++d8) accO[d8][r] *= ar;
      }
    }
    // p bounded by 2^8 (THR); l_ is a per-lane partial (8 keys/iter),
    // cross-quad reduced after the loop.
    float p[2][4];
    #pragma unroll
    for (int n = 0; n < 2; ++n)
      #pragma unroll
      for (int r = 0; r < 4; ++r) {
        p[n][r] = __builtin_amdgcn_exp2f(s[n][r] - m_);
        l_ += p[n][r];
      }

    // ---- mask + pack to PV A-frags (in-lane; no LDS, no shuffle) ----
    f16x4 ap[2];
    #pragma unroll
    for (int n = 0; n < 2; ++n) {
      f16x4 h;
      #pragma unroll
      for (int r = 0; r < 4; ++r)
        h[r] = (_Float16)((rb[n][r] < TH9) ? p[n][r] : 0.0f);
      ap[n] = h;
    }

    // ---- PV: O[16 q x 128 d] += P[16x32] * V[32x128], two 16-key halves ----
    #pragma unroll
    for (int n = 0; n < 2; ++n)
      #pragma unroll
      for (int d8 = 0; d8 < 8; ++d8)
        accO[d8] = __builtin_amdgcn_mfma_f32_16x16x16f16(ap[n], vf[n][d8],
                                                         accO[d8], 0, 0, 0);
  }

  // ---- cross-quad l reduction (each lane held 8 of 32 keys/iter) ----
  l_ += __shfl_xor(l_, 16);
  l_ += __shfl_xor(l_, 32);

  // ---- epilogue: publish m/l (both phases) + kph1's accO; then merge ----
  if (quad == 0) {
    sM[kph * 64 + qsub * 16 + l15] = m_;
    sL[kph * 64 + qsub * 16 + l15] = l_;
  }
  if (kph == 1) {
    #pragma unroll
    for (int d8 = 0; d8 < 8; ++d8)
      #pragma unroll
      for (int r = 0; r < 4; ++r) {
        const int gr = qsub * 16 + quad * 4 + r;
        sO1[gr * D_ + d8 * 16 + l15] = accO[d8][r];
      }
  }
  __syncthreads();
  if (kph == 0) {
    float a0s[4], a1s[4];
    #pragma unroll
    for (int r = 0; r < 4; ++r) {
      const int gr = qsub * 16 + quad * 4 + r;
      const float m0  = sM[gr],      l0v = sL[gr];
      const float m1  = sM[64 + gr], l1v = sL[64 + gr];
      const float mf = fmaxf(m0, m1);
      const float a0 = __builtin_amdgcn_exp2f(m0 - mf);
      const float a1 = __builtin_amdgcn_exp2f(m1 - mf);
      const float inv = 1.0f / ((a0 * l0v + a1 * l1v) * kp);
      a0s[r] = a0 * inv;
      a1s[r] = a1 * inv;
    }
    #pragma unroll
    for (int d8 = 0; d8 < 8; ++d8)
      #pragma unroll
      for (int r = 0; r < 4; ++r) {
        const int gr = qsub * 16 + quad * 4 + r;
        const float o1 = sO1[gr * D_ + d8 * 16 + l15];
        OUT[((size_t)(b * S_ + qt * TQ + gr)) * D_ + d8 * 16 + l15] =
            accO[d8][r] * a0s[r] + o1 * a1s[r];
      }
  }
}

extern "C" void kernel_launch(void* const* d_in, const int* in_sizes, int n_in,
                              void* d_out, int out_size, void* d_ws, size_t ws_size,
                              hipStream_t stream) {
  const float* q   = (const float*)d_in[0];
  const float* k   = (const float*)d_in[1];
  const float* v   = (const float*)d_in[2];
  const float* isf = (const float*)d_in[3];
  const float* dp  = (const float*)d_in[4];
  float* out = (float*)d_out;

  _Float16* kst = (_Float16*)d_ws;                 // 8 MB
  _Float16* vst = kst + KST_ELEMS;                 // 8 MB (dense V^T tiles)

  prep_kv<<<dim3(4096 + 512), dim3(256), 0, stream>>>(k, v, kst, vst);

  attn_mfma_kernel<<<dim3(512), dim3(512), 0, stream>>>(q, kst, vst, isf, dp, out);
}